// Round 1
// baseline (740.778 us; speedup 1.0000x reference)
//
#include <hip/hip_runtime.h>
#include <stdint.h>

#define E_EDGES 262144
#define TILE_M 128
#define MAX_TILES 2064

typedef unsigned short ushort_t;
typedef __attribute__((ext_vector_type(8))) short short8;
typedef __attribute__((ext_vector_type(4))) float f32x4;

// ---- workspace layout (bytes) ----
#define OFF_WT   0                              // bf16 Wt[n=256][k=512] (transposed combined W1;W2)
#define OFF_WP   (512*256*2)                    // 262144: bf16 W_pred frags [16][8][64][8]
#define OFF_PERM (OFF_WP + 16*8*64*8*2)         // 393216: int perm[MAX_TILES*128]
#define OFF_HIST (OFF_PERM + MAX_TILES*128*4)   // 1449984: int[16]
#define OFF_SEG  (OFF_HIST + 64)                // int[17]
#define OFF_CUR  (OFF_SEG + 128)                // int[16]
#define OFF_SUMS (OFF_CUR + 64)                 // float[16]

__device__ __forceinline__ ushort_t f2bf(float f) {
  union { float f; unsigned u; } c; c.f = f;
  unsigned r = c.u + 0x7fffu + ((c.u >> 16) & 1u);   // RNE, finite inputs
  return (ushort_t)(r >> 16);
}

__device__ __forceinline__ void async_copy16(void* lds, const void* g) {
  __builtin_amdgcn_global_load_lds(
      (const __attribute__((address_space(1))) unsigned int*)g,
      (__attribute__((address_space(3))) unsigned int*)lds, 16, 0, 0);
}

// ---- prologue: init perm=-1, build bf16 Wt (transposed), W_pred fragment layout, zero accums ----
__global__ __launch_bounds__(256) void prep_k(const float* __restrict__ W1,
    const float* __restrict__ W2, const float* __restrict__ Wp,
    char* __restrict__ ws) {
  const int i = blockIdx.x * 256 + threadIdx.x;
  int* perm = (int*)(ws + OFF_PERM);
  if (i < MAX_TILES * 128) perm[i] = -1;
  if (i < 512 * 256) {            // Wt[n][k] = (k<256 ? W1[k][n] : W2[k-256][n])
    ushort_t* Wt = (ushort_t*)(ws + OFF_WT);
    const int n = i >> 9, k = i & 511;
    const float v = (k < 256) ? W1[(k << 8) + n] : W2[((k - 256) << 8) + n];
    Wt[i] = f2bf(v);
  }
  if (i < 16 * 8 * 64 * 8) {      // Wp frag: [pair][s][lane][j] = W_pred[pair][32s+8*(lane>>4)+j][lane&15]
    ushort_t* Wpf = (ushort_t*)(ws + OFF_WP);
    const int j = i & 7, l = (i >> 3) & 63, s = (i >> 9) & 7, p = i >> 12;
    const int k = s * 32 + (l >> 4) * 8 + j, c = l & 15;
    Wpf[i] = f2bf(Wp[((p << 8) + k) * 16 + c]);
  }
  if (i < 16) {
    ((int*)(ws + OFF_HIST))[i] = 0;
    ((int*)(ws + OFF_CUR))[i] = 0;
    ((float*)(ws + OFF_SUMS))[i] = 0.f;
  }
}

__global__ __launch_bounds__(256) void hist_k(const int* __restrict__ st,
    const int* __restrict__ dt, char* __restrict__ ws) {
  __shared__ int lh[16];
  int* hist = (int*)(ws + OFF_HIST);
  const int t = threadIdx.x;
  if (t < 16) lh[t] = 0;
  __syncthreads();
  const int i = blockIdx.x * 256 + t;
  if (i < E_EDGES) atomicAdd(&lh[st[i] * 4 + dt[i]], 1);
  __syncthreads();
  if (t < 16 && lh[t] > 0) atomicAdd(&hist[t], lh[t]);
}

__global__ void scan_k(char* __restrict__ ws) {
  if (threadIdx.x == 0) {
    const int* hist = (const int*)(ws + OFF_HIST);
    int* seg = (int*)(ws + OFF_SEG);
    int acc = 0;
    for (int p = 0; p < 16; ++p) {
      seg[p] = acc;
      acc += (hist[p] + 127) & ~127;   // 128-aligned padded segments
    }
    seg[16] = acc;
  }
}

__global__ __launch_bounds__(256) void scatter_k(const int* __restrict__ st,
    const int* __restrict__ dt, char* __restrict__ ws) {
  __shared__ int lh[16], lbase[16];
  const int* seg = (const int*)(ws + OFF_SEG);
  int* cur = (int*)(ws + OFF_CUR);
  int* perm = (int*)(ws + OFF_PERM);
  const int t = threadIdx.x;
  if (t < 16) lh[t] = 0;
  __syncthreads();
  const int i = blockIdx.x * 256 + t;
  int p = 0, r = 0;
  const bool v = (i < E_EDGES);
  if (v) { p = st[i] * 4 + dt[i]; r = atomicAdd(&lh[p], 1); }
  __syncthreads();
  if (t < 16 && lh[t] > 0) lbase[t] = atomicAdd(&cur[t], lh[t]);
  __syncthreads();
  if (v) perm[seg[p] + lbase[p] + r] = i;
}

// ---- fused: gather+GEMM1(bf16 MFMA, K=512, pipelined counted-vmcnt) -> relu ->
//      GEMM2 head -> softmax-CE -> per-pair sums ----
// Pipeline: 16 stages of BK=32. A double-buffered (reg-staged gather, issued 2
// stages ahead), B double-buffered (global_load_lds, issued 1 stage ahead).
// ONE raw s_barrier per stage; waits are counted (vmcnt never drained to 0 in
// the loop). LDS: A 2x10240 + B 2x16384 = 52KB, overlaid by H (64KB) after.
__global__ __launch_bounds__(512, 4) void main_k(
    const float* __restrict__ h_src, const float* __restrict__ h_dst,
    const float* __restrict__ b_dec, const float* __restrict__ b_pred,
    const int* __restrict__ etc_arr, const int* __restrict__ emap,
    char* __restrict__ ws) {
  const ushort_t* Wt = (const ushort_t*)(ws + OFF_WT);
  const short8* Wpf = (const short8*)(ws + OFF_WP);
  const int* perm = (const int*)(ws + OFF_PERM);
  const int* seg = (const int*)(ws + OFF_SEG);
  float* sums = (float*)(ws + OFF_SUMS);

  const int tb = blockIdx.x * TILE_M;
  if (tb >= seg[16]) return;          // beyond padded total: whole block exits
  int pair = 0;
#pragma unroll
  for (int p = 1; p < 16; ++p) pair += (tb >= seg[p]) ? 1 : 0;

  __shared__ __align__(16) char smem[65536];
  // staging (52KB, overlaid by H after K-loop):
  ushort_t* A_buf0 = (ushort_t*)smem;              // [128][40] bf16 (80B rows: 16B-aligned, even bank spread)
  ushort_t* A_buf1 = (ushort_t*)(smem + 10240);
  char* B_buf0 = smem + 20480;                     // 16 chunks x 1KB, fragment order
  char* B_buf1 = smem + 36864;
  ushort_t* H_ls = (ushort_t*)smem;                // [128][256] bf16, reuses staging after K-loop

  const int t = threadIdx.x;
  const int w = t >> 6, lane = t & 63;
  const int quad = lane >> 4, l15 = lane & 15;
  const int wm = w >> 2, wn = w & 3;  // wave tile: rows 64*wm, cols 64*wn

  const int arow = t >> 2, acg = t & 3;
  const int e_stage = perm[tb + arow];
  const int e_safe = (e_stage < 0) ? 0 : e_stage;  // pad rows load row 0 (uniform vmcnt; loss excludes them)

  const f32x4 zero4 = {0.f, 0.f, 0.f, 0.f};
  f32x4 acc[4][4];
#pragma unroll
  for (int i = 0; i < 4; ++i)
#pragma unroll
    for (int j = 0; j < 4; ++j) acc[i][j] = zero4;

  // ---- pipeline helpers (each issues a FIXED number of VMEM ops: counts matter) ----
  auto stage_B = [&](int kt, char* Bb) {           // 2 async ops
#pragma unroll
    for (int ci = 0; ci < 2; ++ci) {
      const int chunk = w * 2 + ci;                // 8 waves x 2 = 16 chunks
      const int n = chunk * 16 + l15;
      const int k = kt * 32 + quad * 8;
      async_copy16(Bb + chunk * 1024, Wt + n * 512 + k);
    }
  };
  auto gather_A = [&](int kt, f32x4* fv) {         // 2 global loads
    const float* srcb = (kt < 8) ? h_src : h_dst;  // kt=16 dummy: valid h_dst addr
    const f32x4* gp = (const f32x4*)(srcb + ((size_t)e_safe << 8) + (kt & 7) * 32 + acg * 8);
    fv[0] = gp[0];
    fv[1] = gp[1];
  };
  auto conv_write = [&](const f32x4* fv, ushort_t* Ab) {
    union { ushort_t u[8]; short8 v; } pk;
#pragma unroll
    for (int q = 0; q < 2; ++q)
#pragma unroll
      for (int x = 0; x < 4; ++x) pk.u[q * 4 + x] = f2bf(fv[q][x]);
    *(short8*)(Ab + arow * 40 + acg * 8) = pk.v;
  };
  auto mma_step = [&](const ushort_t* Ab, const char* Bb) {
    short8 a[4];
#pragma unroll
    for (int i = 0; i < 4; ++i)
      a[i] = *(const short8*)(Ab + (wm * 64 + i * 16 + l15) * 40 + quad * 8);
#pragma unroll
    for (int j = 0; j < 4; ++j) {
      const short8 b = *(const short8*)(Bb + (wn * 4 + j) * 1024 + lane * 16);
#pragma unroll
      for (int i = 0; i < 4; ++i)
        acc[i][j] = __builtin_amdgcn_mfma_f32_16x16x32_bf16(a[i], b, acc[i][j], 0, 0, 0);
    }
  };

  f32x4 ga0[2], ga1[2];
  // ---- prologue: issue GA(0), B(0), GA(1); stage buf0; barrier ----
  gather_A(0, ga0);
  __builtin_amdgcn_sched_barrier(0);
  stage_B(0, B_buf0);
  __builtin_amdgcn_sched_barrier(0);
  gather_A(1, ga1);
  __builtin_amdgcn_sched_barrier(0);
  conv_write(ga0, A_buf0);                         // compiler auto-waits GA(0) (vmcnt(4))
  asm volatile("s_waitcnt vmcnt(2) lgkmcnt(0)" ::: "memory");  // B(0) done, A-write flushed
  __builtin_amdgcn_s_barrier();
  __builtin_amdgcn_sched_barrier(0);

  // ---- main loop: compute stage kt, stage kt+1, issue gather kt+2 ----
#pragma unroll
  for (int kt = 0; kt < 15; ++kt) {
    ushort_t* Acur = (kt & 1) ? A_buf1 : A_buf0;
    ushort_t* Anxt = (kt & 1) ? A_buf0 : A_buf1;
    char* Bcur = (kt & 1) ? B_buf1 : B_buf0;
    char* Bnxt = (kt & 1) ? B_buf0 : B_buf1;
    f32x4* g_nxt = (kt & 1) ? ga0 : ga1;           // holds GA(kt+1)
    f32x4* g_new = (kt & 1) ? ga1 : ga0;           // receives GA(kt+2)

    stage_B(kt + 1, Bnxt);                         // safe: all waves done reading Bnxt (barrier + lgkmcnt(0))
    __builtin_amdgcn_sched_barrier(0);
    gather_A(kt + 2, g_new);                       // kt=14 issues dummy GA(16) to keep counts uniform
    __builtin_amdgcn_sched_barrier(0);
    mma_step(Acur, Bcur);                          // ds_read + 16 MFMA (auto lgkmcnt)
    asm volatile("s_waitcnt vmcnt(4)" ::: "memory");   // GA(kt+1) done; B(kt+1)+GA(kt+2) stay in flight
    conv_write(g_nxt, Anxt);
    asm volatile("s_waitcnt vmcnt(2) lgkmcnt(0)" ::: "memory");  // B(kt+1) done; all LDS ops drained
    __builtin_amdgcn_s_barrier();
    __builtin_amdgcn_sched_barrier(0);
  }
  mma_step(A_buf1, B_buf1);                        // kt=15
  __syncthreads();                                 // full drain before H overlays staging LDS

  // epilogue GEMM1: bias + relu, C-layout (col=lane&15, row=quad*4+reg) -> H_ls bf16
  float bj[4];
#pragma unroll
  for (int j = 0; j < 4; ++j) bj[j] = b_dec[wn * 64 + j * 16 + l15];
#pragma unroll
  for (int i = 0; i < 4; ++i)
#pragma unroll
    for (int j = 0; j < 4; ++j)
#pragma unroll
      for (int r = 0; r < 4; ++r) {
        const int row = wm * 64 + i * 16 + quad * 4 + r;
        const int col = wn * 64 + j * 16 + l15;
        float v = acc[i][j][r] + bj[j];
        v = fmaxf(v, 0.f);
        H_ls[row * 256 + col] = f2bf(v);
      }
  __syncthreads();

  // GEMM2: wave w handles 16 rows; logits[16x16] over K=256
  f32x4 acc2 = zero4;
#pragma unroll
  for (int s = 0; s < 8; ++s) {
    short8 a = *(const short8*)(H_ls + (w * 16 + l15) * 256 + s * 32 + quad * 8);
    short8 b = Wpf[(pair * 8 + s) * 64 + lane];
    acc2 = __builtin_amdgcn_mfma_f32_16x16x32_bf16(a, b, acc2, 0, 0, 0);
  }

  // loss: 16-lane-group softmax-CE (col = lane&15 = class), accumulate per-pair
  const float bp = b_pred[pair * 16 + l15];
  float wacc = 0.f;
#pragma unroll
  for (int r = 0; r < 4; ++r) {
    const int row = w * 16 + quad * 4 + r;
    const int e = perm[tb + row];
    float v = acc2[r] + bp;
    float m = v;
#pragma unroll
    for (int o = 1; o < 16; o <<= 1) m = fmaxf(m, __shfl_xor(m, o, 16));
    float sm = __expf(v - m);
#pragma unroll
    for (int o = 1; o < 16; o <<= 1) sm += __shfl_xor(sm, o, 16);
    int label = 0;
    if (e >= 0) label = emap[pair * 24 + etc_arr[e]];
    const float vlab = __shfl(v, (lane & 48) + label, 64);
    if (e >= 0 && l15 == 0) wacc += m + __logf(sm) - vlab;
  }
  wacc += __shfl_xor(wacc, 16, 64);
  wacc += __shfl_xor(wacc, 32, 64);
  if (lane == 0) atomicAdd(&sums[pair], wacc);
}

__global__ void finalize_k(const char* __restrict__ ws, float* __restrict__ out) {
  const float* sums = (const float*)(ws + OFF_SUMS);
  const int* hist = (const int*)(ws + OFF_HIST);
  const int t = threadIdx.x;
  float g = 0.f, pr = 0.f;
  if (t < 16) {
    const int c = hist[t];
    if (c > 0) { g = sums[t] / (float)c; pr = 1.f; }
  }
#pragma unroll
  for (int o = 1; o < 16; o <<= 1) { g += __shfl_xor(g, o, 64); pr += __shfl_xor(pr, o, 64); }
  if (t == 0) out[0] = g / pr;
}

extern "C" void kernel_launch(void* const* d_in, const int* in_sizes, int n_in,
                              void* d_out, int out_size, void* d_ws, size_t ws_size,
                              hipStream_t stream) {
  const float* h_src  = (const float*)d_in[0];
  const float* h_dst  = (const float*)d_in[1];
  const float* W1     = (const float*)d_in[2];
  const float* W2     = (const float*)d_in[3];
  const float* b_dec  = (const float*)d_in[4];
  const float* W_pred = (const float*)d_in[5];
  const float* b_pred = (const float*)d_in[6];
  const int* st   = (const int*)d_in[7];
  const int* dt   = (const int*)d_in[8];
  const int* etc  = (const int*)d_in[9];
  const int* emap = (const int*)d_in[10];
  char* ws = (char*)d_ws;
  float* out = (float*)d_out;

  prep_k<<<(MAX_TILES * 128 + 255) / 256, 256, 0, stream>>>(W1, W2, W_pred, ws);
  hist_k<<<E_EDGES / 256, 256, 0, stream>>>(st, dt, ws);
  scan_k<<<1, 64, 0, stream>>>(ws);
  scatter_k<<<E_EDGES / 256, 256, 0, stream>>>(st, dt, ws);
  main_k<<<MAX_TILES, 512, 0, stream>>>(h_src, h_dst, b_dec, b_pred, etc, emap, ws);
  finalize_k<<<1, 64, 0, stream>>>(ws, out);
}

// Round 3
// 612.334 us; speedup vs baseline: 1.2098x; 1.2098x over previous
//
#include <hip/hip_runtime.h>
#include <stdint.h>

#define E_EDGES 262144
#define TILE_M 128
#define NBLK (E_EDGES / TILE_M)      // 2048 blocks, natural edge order (no sort)

typedef unsigned short ushort_t;
typedef __attribute__((ext_vector_type(8))) short short8;
typedef __attribute__((ext_vector_type(4))) float f32x4;

// ---- workspace layout (bytes) ----
#define OFF_WT   0                              // bf16 Wt[n=256][k=512] (transposed combined W1;W2)
#define OFF_WP   (512*256*2)                    // bf16 Wpf2[s=8][pair=16][lane=64][jj=8] all-pairs GEMM2 frags
#define OFF_HIST (OFF_WP + 8*16*64*8*2)         // int[16] per-pair counts
#define OFF_SUMS (OFF_HIST + 64)                // float[16] per-pair loss sums

__device__ __forceinline__ ushort_t f2bf(float f) {
  union { float f; unsigned u; } c; c.f = f;
  unsigned r = c.u + 0x7fffu + ((c.u >> 16) & 1u);   // RNE, finite inputs
  return (ushort_t)(r >> 16);
}

__device__ __forceinline__ void async_copy16(void* lds, const void* g) {
  __builtin_amdgcn_global_load_lds(
      (const __attribute__((address_space(1))) unsigned int*)g,
      (__attribute__((address_space(3))) unsigned int*)lds, 16, 0, 0);
}

// ---- prologue: bf16 Wt (transposed), all-pairs W_pred fragments, zero hist/sums ----
__global__ __launch_bounds__(256) void prep_k(const float* __restrict__ W1,
    const float* __restrict__ W2, const float* __restrict__ Wp,
    char* __restrict__ ws) {
  const int i = blockIdx.x * 256 + threadIdx.x;
  if (i < 512 * 256) {            // Wt[n][k] = (k<256 ? W1[k][n] : W2[k-256][n])
    ushort_t* Wt = (ushort_t*)(ws + OFF_WT);
    const int n = i >> 9, k = i & 511;
    const float v = (k < 256) ? W1[(k << 8) + n] : W2[((k - 256) << 8) + n];
    Wt[i] = f2bf(v);
  }
  if (i < 8 * 16 * 64 * 8) {      // Wpf2[s][p][lane][jj] = W_pred[p][s*32+8*(lane>>4)+jj][lane&15]
    ushort_t* Wpf = (ushort_t*)(ws + OFF_WP);
    const int jj = i & 7, l = (i >> 3) & 63, p = (i >> 9) & 15, s = i >> 13;
    const int k = s * 32 + (l >> 4) * 8 + jj, c = l & 15;
    Wpf[i] = f2bf(Wp[((p << 8) + k) * 16 + c]);
  }
  if (i < 16) {
    ((int*)(ws + OFF_HIST))[i] = 0;
    ((float*)(ws + OFF_SUMS))[i] = 0.f;
  }
}

// ---- fused: stream GEMM1(bf16 MFMA, K=512, counted-vmcnt pipeline) -> relu ->
//      GEMM2 all-pairs (N=256=16pair x 16class) -> per-edge select -> softmax-CE
//      -> per-pair loss sums AND per-pair counts (hist folded in) ----
// Natural edge order: all HBM reads are sequential (no random gather).
__global__ __launch_bounds__(512, 4) void main_k(
    const float* __restrict__ h_src, const float* __restrict__ h_dst,
    const float* __restrict__ b_dec, const float* __restrict__ b_pred,
    const int* __restrict__ st, const int* __restrict__ dt,
    const int* __restrict__ etc_arr, const int* __restrict__ emap,
    char* __restrict__ ws) {
  const ushort_t* Wt = (const ushort_t*)(ws + OFF_WT);
  const short8* Wpf2 = (const short8*)(ws + OFF_WP);
  int* hist = (int*)(ws + OFF_HIST);
  float* sums = (float*)(ws + OFF_SUMS);

  const int tb = blockIdx.x * TILE_M;

  __shared__ __align__(16) char smem[65536];
  __shared__ float lsums[16];
  __shared__ int lcnts[16];
  // staging (52KB), overlaid by H after the K-loop:
  ushort_t* A_buf0 = (ushort_t*)smem;              // [128][40] bf16 (80B rows)
  ushort_t* A_buf1 = (ushort_t*)(smem + 10240);
  char* B_buf0 = smem + 20480;                     // 16 chunks x 1KB, fragment order
  char* B_buf1 = smem + 36864;
  ushort_t* H_ls = (ushort_t*)smem;                // [128][256] bf16, XOR-swizzled chunks

  const int t = threadIdx.x;
  const int w = t >> 6, lane = t & 63;
  const int quad = lane >> 4, l15 = lane & 15;
  const int wm = w >> 2, wn = w & 3;  // wave tile: rows 64*wm, cols 64*wn

  const int arow = t >> 2, acg = t & 3;
  const int e_row = tb + arow;                     // natural order: contiguous rows

  if (t < 16) { lsums[t] = 0.f; lcnts[t] = 0; }

  const f32x4 zero4 = {0.f, 0.f, 0.f, 0.f};
  f32x4 acc[4][4];
#pragma unroll
  for (int i = 0; i < 4; ++i)
#pragma unroll
    for (int j = 0; j < 4; ++j) acc[i][j] = zero4;

  // ---- pipeline helpers (each issues a FIXED number of VMEM ops) ----
  auto stage_B = [&](int kt, char* Bb) {           // 2 async ops
#pragma unroll
    for (int ci = 0; ci < 2; ++ci) {
      const int chunk = w * 2 + ci;                // 8 waves x 2 = 16 chunks
      const int n = chunk * 16 + l15;
      const int k = kt * 32 + quad * 8;
      async_copy16(Bb + chunk * 1024, Wt + n * 512 + k);
    }
  };
  auto gather_A = [&](int kt, f32x4* fv) {         // 2 global loads, sequential rows
    const float* srcb = (kt < 8) ? h_src : h_dst;  // kt=16 dummy: valid h_dst addr
    const f32x4* gp = (const f32x4*)(srcb + ((size_t)e_row << 8) + (kt & 7) * 32 + acg * 8);
    fv[0] = gp[0];
    fv[1] = gp[1];
  };
  auto conv_write = [&](const f32x4* fv, ushort_t* Ab) {
    union { ushort_t u[8]; short8 v; } pk;
#pragma unroll
    for (int q = 0; q < 2; ++q)
#pragma unroll
      for (int x = 0; x < 4; ++x) pk.u[q * 4 + x] = f2bf(fv[q][x]);
    *(short8*)(Ab + arow * 40 + acg * 8) = pk.v;
  };
  auto mma_step = [&](const ushort_t* Ab, const char* Bb) {
    short8 a[4];
#pragma unroll
    for (int i = 0; i < 4; ++i)
      a[i] = *(const short8*)(Ab + (wm * 64 + i * 16 + l15) * 40 + quad * 8);
#pragma unroll
    for (int j = 0; j < 4; ++j) {
      const short8 b = *(const short8*)(Bb + (wn * 4 + j) * 1024 + lane * 16);
#pragma unroll
      for (int i = 0; i < 4; ++i)
        acc[i][j] = __builtin_amdgcn_mfma_f32_16x16x32_bf16(a[i], b, acc[i][j], 0, 0, 0);
    }
  };

  f32x4 ga0[2], ga1[2];
  // ---- prologue: issue GA(0), B(0), GA(1); stage buf0; barrier ----
  gather_A(0, ga0);
  __builtin_amdgcn_sched_barrier(0);
  stage_B(0, B_buf0);
  __builtin_amdgcn_sched_barrier(0);
  gather_A(1, ga1);
  __builtin_amdgcn_sched_barrier(0);
  conv_write(ga0, A_buf0);                         // compiler auto-waits GA(0)
  asm volatile("s_waitcnt vmcnt(2) lgkmcnt(0)" ::: "memory");  // B(0) done, A-write flushed
  __builtin_amdgcn_s_barrier();
  __builtin_amdgcn_sched_barrier(0);

  // ---- main loop: compute stage kt, stage kt+1, issue gather kt+2 ----
#pragma unroll
  for (int kt = 0; kt < 15; ++kt) {
    ushort_t* Acur = (kt & 1) ? A_buf1 : A_buf0;
    ushort_t* Anxt = (kt & 1) ? A_buf0 : A_buf1;
    char* Bcur = (kt & 1) ? B_buf1 : B_buf0;
    char* Bnxt = (kt & 1) ? B_buf0 : B_buf1;
    f32x4* g_nxt = (kt & 1) ? ga0 : ga1;           // holds GA(kt+1)
    f32x4* g_new = (kt & 1) ? ga1 : ga0;           // receives GA(kt+2)

    stage_B(kt + 1, Bnxt);
    __builtin_amdgcn_sched_barrier(0);
    gather_A(kt + 2, g_new);
    __builtin_amdgcn_sched_barrier(0);
    mma_step(Acur, Bcur);
    asm volatile("s_waitcnt vmcnt(4)" ::: "memory");   // GA(kt+1) done; B(kt+1)+GA(kt+2) in flight
    conv_write(g_nxt, Anxt);
    asm volatile("s_waitcnt vmcnt(2) lgkmcnt(0)" ::: "memory");  // B(kt+1) done; LDS drained
    __builtin_amdgcn_s_barrier();
    __builtin_amdgcn_sched_barrier(0);
  }
  mma_step(A_buf1, B_buf1);                        // kt=15
  __syncthreads();                                 // full drain before H overlays staging LDS

  // epilogue GEMM1: bias + relu -> H_ls bf16, XOR-swizzled 16B chunks:
  // addr(row,col) = row*256 + ((col>>3 ^ (row&7))<<3) + (col&7)
  float bj[4];
#pragma unroll
  for (int j = 0; j < 4; ++j) bj[j] = b_dec[wn * 64 + j * 16 + l15];
#pragma unroll
  for (int i = 0; i < 4; ++i)
#pragma unroll
    for (int j = 0; j < 4; ++j)
#pragma unroll
      for (int r = 0; r < 4; ++r) {
        const int row = wm * 64 + i * 16 + quad * 4 + r;
        const int col = wn * 64 + j * 16 + l15;
        float v = acc[i][j][r] + bj[j];
        v = fmaxf(v, 0.f);
        H_ls[row * 256 + (((col >> 3) ^ (row & 7)) << 3) + (col & 7)] = f2bf(v);
      }
  __syncthreads();

  // GEMM2 all-pairs: M=128, N=256 (16 pairs x 16 classes), K=256.
  // Wave (wm,wn): rows [64wm,64wm+64), cols [64wn,64wn+64) = pairs [4wn,4wn+4).
  f32x4 acc2[4][4];
#pragma unroll
  for (int i = 0; i < 4; ++i)
#pragma unroll
    for (int j = 0; j < 4; ++j) acc2[i][j] = zero4;
#pragma unroll
  for (int s = 0; s < 8; ++s) {
    short8 a[4], b[4];
#pragma unroll
    for (int x = 0; x < 4; ++x) {
      const int row = wm * 64 + x * 16 + l15;
      a[x] = *(const short8*)(H_ls + row * 256 + (((s * 4 + quad) ^ (row & 7)) << 3));
    }
#pragma unroll
    for (int j = 0; j < 4; ++j)
      b[j] = Wpf2[(s * 16 + wn * 4 + j) * 64 + lane];   // L2-hot, 128KB shared by all blocks
#pragma unroll
    for (int x = 0; x < 4; ++x)
#pragma unroll
      for (int j = 0; j < 4; ++j)
        acc2[x][j] = __builtin_amdgcn_mfma_f32_16x16x32_bf16(a[x], b[j], acc2[x][j], 0, 0, 0);
  }

  // CE: one softmax per owned row; select the row's own pair block via cndmask.
  float bpj[4];
#pragma unroll
  for (int j = 0; j < 4; ++j) bpj[j] = b_pred[(wn * 4 + j) * 16 + l15];
  float wsum[4] = {0.f, 0.f, 0.f, 0.f};
  int wcnt[4] = {0, 0, 0, 0};
#pragma unroll
  for (int i = 0; i < 4; ++i)
#pragma unroll
    for (int r = 0; r < 4; ++r) {
      const int row = wm * 64 + i * 16 + quad * 4 + r;
      const int e = tb + row;
      const int pe = st[e] * 4 + dt[e];              // uniform across the 16-lane group
      float v = 0.f;
#pragma unroll
      for (int j = 0; j < 4; ++j) {
        const bool hit = (pe == wn * 4 + j);
        v = hit ? (acc2[i][j][r] + bpj[j]) : v;
      }
      float m = v;
#pragma unroll
      for (int o = 1; o < 16; o <<= 1) m = fmaxf(m, __shfl_xor(m, o, 16));
      float sm = __expf(v - m);
#pragma unroll
      for (int o = 1; o < 16; o <<= 1) sm += __shfl_xor(sm, o, 16);
      const int label = emap[pe * 24 + etc_arr[e]];
      const float vlab = __shfl(v, (lane & 48) + label, 64);
      const float loss = m + __logf(sm) - vlab;
#pragma unroll
      for (int j = 0; j < 4; ++j)
        if (pe == wn * 4 + j && l15 == 0) { wsum[j] += loss; wcnt[j] += 1; }
    }
  __syncthreads();   // lsums/lcnts zero-init visible (done pre-K-loop)
#pragma unroll
  for (int j = 0; j < 4; ++j) {
    float wv = wsum[j];
    int cv = wcnt[j];
    wv += __shfl_xor(wv, 16, 64);
    wv += __shfl_xor(wv, 32, 64);
    cv += __shfl_xor(cv, 16, 64);
    cv += __shfl_xor(cv, 32, 64);
    if (lane == 0 && cv > 0) {
      atomicAdd(&lsums[wn * 4 + j], wv);
      atomicAdd(&lcnts[wn * 4 + j], cv);
    }
  }
  __syncthreads();
  if (t < 16 && lcnts[t] > 0) {
    atomicAdd(&sums[t], lsums[t]);
    atomicAdd(&hist[t], lcnts[t]);
  }
}

__global__ void finalize_k(const char* __restrict__ ws, float* __restrict__ out) {
  const float* sums = (const float*)(ws + OFF_SUMS);
  const int* hist = (const int*)(ws + OFF_HIST);
  const int t = threadIdx.x;
  float g = 0.f, pr = 0.f;
  if (t < 16) {
    const int c = hist[t];
    if (c > 0) { g = sums[t] / (float)c; pr = 1.f; }
  }
#pragma unroll
  for (int o = 1; o < 16; o <<= 1) { g += __shfl_xor(g, o, 64); pr += __shfl_xor(pr, o, 64); }
  if (t == 0) out[0] = g / pr;
}

extern "C" void kernel_launch(void* const* d_in, const int* in_sizes, int n_in,
                              void* d_out, int out_size, void* d_ws, size_t ws_size,
                              hipStream_t stream) {
  const float* h_src  = (const float*)d_in[0];
  const float* h_dst  = (const float*)d_in[1];
  const float* W1     = (const float*)d_in[2];
  const float* W2     = (const float*)d_in[3];
  const float* b_dec  = (const float*)d_in[4];
  const float* W_pred = (const float*)d_in[5];
  const float* b_pred = (const float*)d_in[6];
  const int* st   = (const int*)d_in[7];
  const int* dt   = (const int*)d_in[8];
  const int* etc  = (const int*)d_in[9];
  const int* emap = (const int*)d_in[10];
  char* ws = (char*)d_ws;
  float* out = (float*)d_out;

  prep_k<<<512, 256, 0, stream>>>(W1, W2, W_pred, ws);
  main_k<<<NBLK, 512, 0, stream>>>(h_src, h_dst, b_dec, b_pred, st, dt, etc, emap, ws);
  finalize_k<<<1, 64, 0, stream>>>(ws, out);
}